// Round 10
// baseline (251.490 us; speedup 1.0000x reference)
//
#include <hip/hip_runtime.h>

#define N_FLOWS 20
#define DIM 4
#define ITEMS 2            // samples per thread per tile (one rcp-pair per flow)
#define BLOCK 256
#define PBLOCKS 2048       // persistent blocks: 8 workgroups/CU on 256 CUs
#define TILE (BLOCK * ITEMS)   // 512 float4 samples per tile (8 KB LDS)

typedef float v2f __attribute__((ext_vector_type(2)));
typedef float v4f __attribute__((ext_vector_type(4)));   // native vector for NT stores

// ---------------------------------------------------------------------------
// Async global->LDS DMA (16 B per lane). No destination VGPR => no register
// dependency => the compiler cannot be forced into an early vmcnt wait by
// register pressure (rounds 2/5/8 lesson: every reg-carried prefetch got
// collapsed/serialized; VGPR_Count 24 proved the pipeline never materialized).
// LDS dest rule (m104): wave-uniform base + lane*16 -- our per-lane
// &buf[tid] = base + (wid*64)*16 + lane*16 satisfies it exactly.
// ---------------------------------------------------------------------------
__device__ __forceinline__ void async_cp16(const float4* g, float4* l) {
    __builtin_amdgcn_global_load_lds(
        (__attribute__((address_space(1))) void*)(float4*)g,
        (__attribute__((address_space(3))) void*)l,
        16, 0, 0);
}

// ---------------------------------------------------------------------------
// Setup: one tiny block precomputes per-flow constants for the d-space
// recurrence. d_f := x - x0_f;  s = 1 + beta/(alpha + ||d_f||);
// d_{f+1} = s*d_f + c_f, with c_f = x0_f - x0_{f+1} (f<19), c_19 = x0_19
// so the final update directly produces x_20.
// ws layout per flow f (8 floats): [c.x,c.y,c.z,c.w, alpha, beta, 0, 0]
// slot f==N_FLOWS: [x0_0 (4 floats), 0,0,0,0]  (for d_0 init)
// ---------------------------------------------------------------------------
__global__ void radial_setup(const float* __restrict__ x0s,
                             const float* __restrict__ alpha_primes,
                             const float* __restrict__ beta_primes,
                             float* __restrict__ ws) {
    int f = threadIdx.x;
    if (f < N_FLOWS) {
        float alpha = __logf(1.0f + __expf(alpha_primes[f]));
        float beta  = __logf(1.0f + __expf(beta_primes[f])) - alpha;
        float* p = ws + 8 * f;
        const bool last = (f == N_FLOWS - 1);
#pragma unroll
        for (int j = 0; j < 4; ++j)
            p[j] = x0s[4 * f + j] - (last ? 0.0f : x0s[4 * (f + 1) + j]);
        p[4] = alpha;
        p[5] = beta;
        p[6] = 0.0f;
        p[7] = 0.0f;
    } else if (f == N_FLOWS) {
        float* p = ws + 8 * N_FLOWS;
        p[0] = x0s[0]; p[1] = x0s[1]; p[2] = x0s[2]; p[3] = x0s[3];
        p[4] = 0.0f; p[5] = 0.0f; p[6] = 0.0f; p[7] = 0.0f;
    }
}

// One flow on the resident pair: 2x {pk_mul, pk_fma, add, v_sqrt, add} -> D_i,
// one shared v_rcp via pair batch-inversion (3 muls), 2x {fma, 2x pk_fma}.
#define FLOWP(F)                                                               \
    do {                                                                       \
        float4 c  = P[2 * (F)];        /* uniform -> s_load */                 \
        float4 ab = P[2 * (F) + 1];                                            \
        v2f c01 = (v2f){c.x, c.y};                                             \
        v2f c23 = (v2f){c.z, c.w};                                             \
        v2f q0 = a0 * a0; q0 += b0 * b0;                                       \
        v2f q1 = a1 * a1; q1 += b1 * b1;                                       \
        float D0 = ab.x + __builtin_amdgcn_sqrtf(q0.x + q0.y);                 \
        float D1 = ab.x + __builtin_amdgcn_sqrtf(q1.x + q1.y);                 \
        float inv = __builtin_amdgcn_rcpf(D0 * D1);                            \
        float s0 = __builtin_fmaf(ab.y, inv * D1, 1.0f);                       \
        float s1 = __builtin_fmaf(ab.y, inv * D0, 1.0f);                       \
        v2f sv;                                                                \
        sv = (v2f){s0, s0}; a0 = sv * a0 + c01; b0 = sv * b0 + c23;            \
        sv = (v2f){s1, s1}; a1 = sv * a1 + c01; b1 = sv * b1 + c23;            \
    } while (0)

// Read this wave's two items from SRCBUF (ds_read_b128 x2; the only wait the
// compiler must insert is DMA-completion for SRCBUF), run 20 flows, NT-store.
#define COMPSTORE(SRCBUF, IDXV)                                                \
    do {                                                                       \
        float4 v0 = SRCBUF[tid];                                               \
        float4 v1 = SRCBUF[tid + BLOCK];                                       \
        v2f a0 = (v2f){v0.x, v0.y} - z01;                                      \
        v2f b0 = (v2f){v0.z, v0.w} - z23;                                      \
        v2f a1 = (v2f){v1.x, v1.y} - z01;                                      \
        v2f b1 = (v2f){v1.z, v1.w} - z23;                                      \
        FLOWP(0);  FLOWP(1);  FLOWP(2);  FLOWP(3);  FLOWP(4);                  \
        FLOWP(5);  FLOWP(6);  FLOWP(7);  FLOWP(8);  FLOWP(9);                  \
        FLOWP(10); FLOWP(11); FLOWP(12); FLOWP(13); FLOWP(14);                 \
        FLOWP(15); FLOWP(16); FLOWP(17); FLOWP(18); FLOWP(19);                 \
        v4f o;                                                                 \
        o = (v4f){a0.x, a0.y, b0.x, b0.y};                                     \
        __builtin_nontemporal_store(o, Ovv + (IDXV));                          \
        o = (v4f){a1.x, a1.y, b1.x, b1.y};                                     \
        __builtin_nontemporal_store(o, Ovv + (IDXV) + BLOCK);                  \
    } while (0)

// Issue the 2 async DMAs of tile at per-lane index NIDX into DSTBUF.
#define STAGE(DSTBUF, NIDX)                                                    \
    do {                                                                       \
        async_cp16(Xv + (NIDX),         &DSTBUF[tid]);                         \
        async_cp16(Xv + (NIDX) + BLOCK, &DSTBUF[tid + BLOCK]);                 \
    } while (0)

// ---------------------------------------------------------------------------
// Persistent main: each block owns T consecutive tiles, LDS double-buffered
// via named bufA/bufB (named => waitcnt pass can track the two DMA targets
// separately). Each wave's lanes touch only their own contiguous LDS region,
// so there is NO __syncthreads anywhere -- waves free-run; the only ordering
// is the per-wave DMA-completion wait before the ds_read of the CURRENT
// buffer, while the NEXT buffer's DMA stays in flight under the whole
// ~1600-cycle flow chain.
// ---------------------------------------------------------------------------
__global__ __launch_bounds__(BLOCK) void radial_main(
    const float4* __restrict__ Xv,
    const float4* __restrict__ P,
    float4* __restrict__ Ov,
    int T)
{
    __shared__ float4 bufA[TILE];
    __shared__ float4 bufB[TILE];

    v4f* __restrict__ Ovv = (v4f*)Ov;     // native-vector alias for NT stores

    float4 z = P[2 * N_FLOWS];            // x0_0 (uniform -> s_load)
    v2f z01 = (v2f){z.x, z.y};
    v2f z23 = (v2f){z.z, z.w};

    const unsigned tid = threadIdx.x;
    unsigned idx = (unsigned)blockIdx.x * (unsigned)T * TILE + tid;

    STAGE(bufA, idx);                     // prologue: tile 0 -> bufA

    int t = 0;
    for (;;) {
        {   // compute tile t from bufA; prefetch t+1 -> bufB
            unsigned nidx = idx + ((t + 1 < T) ? (unsigned)TILE : 0u);
            STAGE(bufB, nidx);
            COMPSTORE(bufA, idx);
        }
        if (++t >= T) break;
        idx += TILE;
        {   // compute tile t from bufB; prefetch t+1 -> bufA
            unsigned nidx = idx + ((t + 1 < T) ? (unsigned)TILE : 0u);
            STAGE(bufA, nidx);
            COMPSTORE(bufB, idx);
        }
        if (++t >= T) break;
        idx += TILE;
    }
}

// Generic tail: one guarded sample per thread (grid is 0 for BATCH=2^23).
__global__ void radial_tail(const float4* __restrict__ Xv,
                            const float4* __restrict__ P,
                            float4* __restrict__ Ov,
                            int start, int batch) {
    int idx = start + blockIdx.x * blockDim.x + threadIdx.x;
    if (idx >= batch) return;
    float4 z = P[2 * N_FLOWS];
    float4 v = Xv[idx];
    float dx = v.x - z.x, dy = v.y - z.y, dz = v.z - z.z, dw = v.w - z.w;
#pragma unroll
    for (int f = 0; f < N_FLOWS; ++f) {
        float4 c  = P[2 * f];
        float4 ab = P[2 * f + 1];
        float r2 = dx * dx + dy * dy + dz * dz + dw * dw;
        float r  = __builtin_amdgcn_sqrtf(r2);
        float s  = __builtin_fmaf(ab.y, __builtin_amdgcn_rcpf(ab.x + r), 1.0f);
        dx = s * dx + c.x; dy = s * dy + c.y;
        dz = s * dz + c.z; dw = s * dw + c.w;
    }
    float4 o; o.x = dx; o.y = dy; o.z = dz; o.w = dw;
    Ov[idx] = o;
}

extern "C" void kernel_launch(void* const* d_in, const int* in_sizes, int n_in,
                              void* d_out, int out_size, void* d_ws, size_t ws_size,
                              hipStream_t stream) {
    const float* X   = (const float*)d_in[0];
    const float* x0s = (const float*)d_in[1];
    const float* ap  = (const float*)d_in[2];
    const float* bp  = (const float*)d_in[3];
    float* out = (float*)d_out;
    float* ws  = (float*)d_ws;

    int batch = in_sizes[0] / DIM;     // 8388608
    int tiles = batch / TILE;          // 16384 for BATCH=2^23

    radial_setup<<<1, 64, 0, stream>>>(x0s, ap, bp, ws);

    int done = 0;
    if (tiles >= PBLOCKS) {
        int T = tiles / PBLOCKS;       // 8
        radial_main<<<PBLOCKS, BLOCK, 0, stream>>>(
            (const float4*)X, (const float4*)ws, (float4*)out, T);
        done = PBLOCKS * T * TILE;
    } else if (tiles > 0) {
        radial_main<<<tiles, BLOCK, 0, stream>>>(
            (const float4*)X, (const float4*)ws, (float4*)out, 1);
        done = tiles * TILE;
    }

    int rem = batch - done;
    if (rem > 0)
        radial_tail<<<(rem + 255) / 256, 256, 0, stream>>>(
            (const float4*)X, (const float4*)ws, (float4*)out, done, batch);
}